// Round 4
// baseline (419.365 us; speedup 1.0000x reference)
//
#include <hip/hip_runtime.h>

#define E_TOTAL 600000
#define NTILES 9375   // 600000 / 64, exact
#define NB 512        // persistent blocks: 2 resident per CU x 256 CUs

typedef __attribute__((ext_vector_type(8))) short short8;
typedef __attribute__((ext_vector_type(4))) short short4v;
typedef __attribute__((ext_vector_type(4))) float f32x4;

// async global->LDS, 16B per lane, dest = uniform base + lane*16 (HW rule)
#define GLOAD_LDS16(g, l) \
  __builtin_amdgcn_global_load_lds((const __attribute__((address_space(1))) void*)(g), \
                                   (__attribute__((address_space(3))) void*)(l), 16, 0, 0)

__device__ __forceinline__ unsigned f2bf_u(float f) {
  union { float f; unsigned u; } v; v.f = f;
  return (v.u + 0x7fffu + ((v.u >> 16) & 1u)) >> 16;  // RNE
}

// LDS-only barrier: drain ds ops, do NOT drain vmcnt (gathers stay in flight).
__device__ __forceinline__ void ldsBarrier() {
  asm volatile("s_waitcnt lgkmcnt(0)\n\ts_barrier" ::: "memory");
}

// ---- weight prep: tiled transpose+cast. W1[k][n]->W1t[n][k] bf16, W2 likewise ----
__global__ __launch_bounds__(256) void prep_weights(
    const float* __restrict__ W1, const float* __restrict__ W2,
    unsigned short* __restrict__ W1t, unsigned short* __restrict__ W2t) {
  __shared__ float t[32][33];
  int bid = blockIdx.x;
  const float* S; unsigned short* D; int k0, n0, N;
  if (bid < 64) { S = W1; D = W1t; N = 256; k0 = (bid >> 3) * 32; n0 = (bid & 7) * 32; }
  else { bid -= 64; S = W2; D = W2t; N = 64; k0 = (bid >> 1) * 32; n0 = (bid & 1) * 32; }
  int tx = threadIdx.x & 31, ty = threadIdx.x >> 5;
#pragma unroll
  for (int i = 0; i < 32; i += 8) t[ty + i][tx] = S[(k0 + ty + i) * N + n0 + tx];
  __syncthreads();
#pragma unroll
  for (int i = 0; i < 32; i += 8)
    D[(n0 + ty + i) * 256 + k0 + tx] = (unsigned short)f2bf_u(t[tx][ty + i]);
}

// ---- x -> bf16 pre-convert (12.8 MB, L3-resident gather footprint) ----
__global__ __launch_bounds__(256) void prep_x(const float* __restrict__ x,
                                              unsigned short* __restrict__ xb) {
  int i = (blockIdx.x * 256 + threadIdx.x) * 4;
  f32x4 v = *(const f32x4*)(x + i);
  short4v s;
#pragma unroll
  for (int j = 0; j < 4; ++j) s[j] = (short)f2bf_u(v[j]);
  *(short4v*)(xb + i) = s;
}

// ---- fused edge MLP ----
// Persistent, 64-edge tiles, double-buffered LDS (2 x 32KB), W1/W2 register-
// resident (loaded once), gather via global_load_lds with XOR chunk swizzle:
//   LDS row r (512B, 32 x 16B chunks): data chunk c lives at slot c ^ (r&7).
//   Gather applies the permutation on the per-lane GLOBAL address (dest must be
//   linear); every ds_read/ds_write applies the same XOR. Conflict-free.
// Per tile vmem: 8 global_load_lds + 8 idx + 4 stores; the ONLY vmem wait is
// one vmcnt(0) at the tile-end barrier, giving gather(t+NB) the whole tile of
// latency cover. Phase 1 has zero global loads.
__global__ __launch_bounds__(256, 2) void edge_mlp(
    const unsigned short* __restrict__ xb, const int* __restrict__ ei,
    const unsigned short* __restrict__ W1t, const unsigned short* __restrict__ W2t,
    const float* __restrict__ b1, const float* __restrict__ b2,
    float* __restrict__ out) {
  __shared__ __align__(16) unsigned short lds[2 * 16384];  // 2 x (64 rows x 256 shorts)
  __shared__ float ldsb1[256];
  __shared__ float ldsb2[64];

  const int tid = threadIdx.x;
  const int lane = tid & 63;
  const int w = tid >> 6;    // wave 0..3
  const int m = lane & 15;
  const int q = lane >> 4;
  const int rl = lane >> 5;  // gather: row-within-pair (each instr loads 2 rows)
  const int gc = lane & 15;  // gather: 16B chunk within the node half
  // slot chunk (lane&31): <16 -> src half of the row, else dst half (XOR by
  // (r&7) only permutes within 8-chunk groups, so the half is slot-determined)
  const int* __restrict__ idxp = ((lane & 31) < 16) ? ei : (ei + E_TOTAL);

  ldsb1[tid] = b1[tid];
  if (tid < 64) ldsb2[tid] = b2[tid];

  // ---- tile-invariant weight slices -> registers (once per block) ----
  short8 w1r[8][4];
  {
    int w1off[4];
#pragma unroll
    for (int nt = 0; nt < 4; ++nt) w1off[nt] = ((w * 4 + nt) * 16 + m) * 256 + q * 8;
#pragma unroll
    for (int kk = 0; kk < 8; ++kk)
#pragma unroll
      for (int nt = 0; nt < 4; ++nt) w1r[kk][nt] = *(const short8*)&W1t[w1off[nt] + kk * 32];
  }
  short8 w2r[8];
  {
    const int w2off = (w * 16 + m) * 256 + q * 8;
#pragma unroll
    for (int kk = 0; kk < 8; ++kk) w2r[kk] = *(const short8*)&W2t[w2off + kk * 32];
  }

  int t = blockIdx.x;

  // ---- prologue: idx(t), gather(t)->buf0, idx(t+NB) ----
  int idxv[8];
#pragma unroll
  for (int i = 0; i < 8; ++i) idxv[i] = idxp[t * 64 + w * 16 + i * 2 + rl];
#pragma unroll
  for (int i = 0; i < 8; ++i) {
    const unsigned short* g = xb + idxv[i] * 128 + ((gc ^ ((i * 2 + rl) & 7)) << 3);
    GLOAD_LDS16(g, &lds[(w * 16 + i * 2) * 256]);
  }
  if (t + NB < NTILES) {
#pragma unroll
    for (int i = 0; i < 8; ++i) idxv[i] = idxp[(t + NB) * 64 + w * 16 + i * 2 + rl];
  }
  asm volatile("s_waitcnt vmcnt(0) lgkmcnt(0)\n\ts_barrier" ::: "memory");

  unsigned cur = 0;
  for (; t < NTILES; t += NB) {
    const unsigned nxt = cur ^ 16384;

    // ---- A: issue gather(t+NB) into nxt (in flight across the whole tile) ----
    if (t + NB < NTILES) {
#pragma unroll
      for (int i = 0; i < 8; ++i) {
        const unsigned short* g = xb + idxv[i] * 128 + ((gc ^ ((i * 2 + rl) & 7)) << 3);
        GLOAD_LDS16(g, &lds[nxt + (w * 16 + i * 2) * 256]);
      }
      if (t + 2 * NB < NTILES) {
#pragma unroll
        for (int i = 0; i < 8; ++i) idxv[i] = idxp[(t + 2 * NB) * 64 + w * 16 + i * 2 + rl];
      }
    }

    // ---- phase 1: D[n1][e] = sum_k W1[n1][k]*feat[e][k] — zero global loads ----
    f32x4 acc[4][4];
#pragma unroll
    for (int nt = 0; nt < 4; ++nt)
#pragma unroll
      for (int mt = 0; mt < 4; ++mt) acc[nt][mt] = (f32x4){0.f, 0.f, 0.f, 0.f};

#pragma unroll
    for (int kk = 0; kk < 8; ++kk) {
      short8 f[4];
#pragma unroll
      for (int mt = 0; mt < 4; ++mt)
        f[mt] = *(const short8*)&lds[cur + (mt * 16 + m) * 256 +
                                     ((kk * 32 + q * 8) ^ ((m & 7) << 3))];
#pragma unroll
      for (int nt = 0; nt < 4; ++nt)
#pragma unroll
        for (int mt = 0; mt < 4; ++mt)
          acc[nt][mt] = __builtin_amdgcn_mfma_f32_16x16x32_bf16(w1r[kk][nt], f[mt], acc[nt][mt], 0, 0, 0);
    }

    ldsBarrier();  // feat reads done; safe to overwrite with hidden

    // ---- hidden: bias + relu + packed bf16 write back into cur (swizzled) ----
#pragma unroll
    for (int nt = 0; nt < 4; ++nt) {
      f32x4 bias = *(const f32x4*)&ldsb1[w * 64 + nt * 16 + q * 4];
#pragma unroll
      for (int mt = 0; mt < 4; ++mt) {
        float h0 = fmaxf(acc[nt][mt][0] + bias[0], 0.f);
        float h1 = fmaxf(acc[nt][mt][1] + bias[1], 0.f);
        float h2 = fmaxf(acc[nt][mt][2] + bias[2], 0.f);
        float h3 = fmaxf(acc[nt][mt][3] + bias[3], 0.f);
        uint2 pk;
        pk.x = f2bf_u(h0) | (f2bf_u(h1) << 16);
        pk.y = f2bf_u(h2) | (f2bf_u(h3) << 16);
        *(uint2*)&lds[cur + (mt * 16 + m) * 256 +
                      ((w * 64 + nt * 16 + q * 4) ^ ((m & 7) << 3))] = pk;
      }
    }

    ldsBarrier();  // hidden visible

    // ---- phase 2: D[n2][e] = sum_k W2[n2][k]*hidden[e][k] ----
    f32x4 acc2[4];
#pragma unroll
    for (int mt = 0; mt < 4; ++mt) acc2[mt] = (f32x4){0.f, 0.f, 0.f, 0.f};
#pragma unroll
    for (int kk = 0; kk < 8; ++kk) {
#pragma unroll
      for (int mt = 0; mt < 4; ++mt) {
        short8 h = *(const short8*)&lds[cur + (mt * 16 + m) * 256 +
                                        ((kk * 32 + q * 8) ^ ((m & 7) << 3))];
        acc2[mt] = __builtin_amdgcn_mfma_f32_16x16x32_bf16(w2r[kk], h, acc2[mt], 0, 0, 0);
      }
    }

    f32x4 b2v = *(const f32x4*)&ldsb2[w * 16 + q * 4];
#pragma unroll
    for (int mt = 0; mt < 4; ++mt) {
      f32x4 o;
#pragma unroll
      for (int r = 0; r < 4; ++r) o[r] = acc2[mt][r] + b2v[r];
      *(f32x4*)&out[(t * 64 + mt * 16 + m) * 64 + w * 16 + q * 4] = o;
    }

    // tile-end: gather(t+NB) landed + phase2 LDS reads done on all waves
    asm volatile("s_waitcnt vmcnt(0) lgkmcnt(0)\n\ts_barrier" ::: "memory");
    cur = nxt;
  }
}

extern "C" void kernel_launch(void* const* d_in, const int* in_sizes, int n_in,
                              void* d_out, int out_size, void* d_ws, size_t ws_size,
                              hipStream_t stream) {
  const float* x  = (const float*)d_in[0];
  const int*   ei = (const int*)d_in[1];
  const float* W1 = (const float*)d_in[2];
  const float* b1 = (const float*)d_in[3];
  const float* W2 = (const float*)d_in[4];
  const float* b2 = (const float*)d_in[5];
  float* out = (float*)d_out;

  unsigned short* W1t = (unsigned short*)d_ws;   // 256*256 bf16
  unsigned short* W2t = W1t + 256 * 256;         // 64*256 bf16
  unsigned short* xb  = W2t + 64 * 256;          // 50000*128 bf16 (12.8 MB)

  prep_weights<<<80, 256, 0, stream>>>(W1, W2, W1t, W2t);
  prep_x<<<6250, 256, 0, stream>>>(x, xb);       // 6250*256*4 = 6.4M elems exactly
  edge_mlp<<<NB, 256, 0, stream>>>(xb, ei, W1t, W2t, b1, b2, out);
}

// Round 5
// 304.939 us; speedup vs baseline: 1.3752x; 1.3752x over previous
//
#include <hip/hip_runtime.h>

#define E_TOTAL 600000
#define N_NODES 50000
#define ETILE 96
#define NETILES 6250        // 600000 / 96 exact, no tail
#define NNT 391             // ceil(50000/128) node tiles
#define LDH2 136            // node-kernel x-tile row stride (shorts), 272B
#define LDH3 264            // edge-kernel hidden row stride (shorts), 528B

typedef __attribute__((ext_vector_type(8))) short short8;
typedef __attribute__((ext_vector_type(8))) _Float16 half8;
typedef __attribute__((ext_vector_type(4))) float f32x4;

__device__ __forceinline__ unsigned f2bf_u(float f) {
  union { float f; unsigned u; } v; v.f = f;
  return (v.u + 0x7fffu + ((v.u >> 16) & 1u)) >> 16;  // RNE
}
__device__ __forceinline__ unsigned short f2h_u(float f) {
  union { _Float16 h; unsigned short u; } v; v.h = (_Float16)f;  // v_cvt_f16_f32 RNE
  return v.u;
}

// ---- prep: W1 -> W1c[c][k] bf16 (c = n + 256*(k>=128), k'=k&127, [512][128]);
//            W2 -> W2t2[n][k] f16 [64][256]; b1 -> b1h f16 ----
__global__ __launch_bounds__(256) void prep(
    const float* __restrict__ W1, const float* __restrict__ W2,
    const float* __restrict__ b1,
    unsigned short* __restrict__ W1c, unsigned short* __restrict__ W2t2,
    unsigned short* __restrict__ b1h) {
  __shared__ float t[32][33];
  int bid = blockIdx.x;
  int tx = threadIdx.x & 31, ty = threadIdx.x >> 5;
  if (bid < 64) {
    int k0 = (bid >> 3) * 32, n0 = (bid & 7) * 32;
#pragma unroll
    for (int i = 0; i < 32; i += 8) t[ty + i][tx] = W1[(k0 + ty + i) * 256 + n0 + tx];
    __syncthreads();
    int coff = (k0 >= 128) ? 256 : 0;
#pragma unroll
    for (int i = 0; i < 32; i += 8)
      W1c[(n0 + ty + i + coff) * 128 + (k0 & 127) + tx] = (unsigned short)f2bf_u(t[tx][ty + i]);
  } else if (bid < 80) {
    int b = bid - 64;
    int k0 = (b >> 1) * 32, n0 = (b & 1) * 32;
#pragma unroll
    for (int i = 0; i < 32; i += 8) t[ty + i][tx] = W2[(k0 + ty + i) * 64 + n0 + tx];
    __syncthreads();
#pragma unroll
    for (int i = 0; i < 32; i += 8)
      W2t2[(n0 + ty + i) * 256 + k0 + tx] = f2h_u(t[tx][ty + i]);
  } else {
    b1h[threadIdx.x] = f2h_u(b1[threadIdx.x]);
  }
}

// ---- node kernel: UV[n][c] f16, c<256: u = x@W1[:128]; c>=256: v = x@W1[128:] ----
// Per block: 128-node tile x 256 c-cols (chalf). Round-3-proven phase-1 shape:
// 4 waves x (c-span 64), acc[4][8], K=128 (4 kk steps), wa double-buffered.
__global__ __launch_bounds__(256, 2) void node_uv(
    const float* __restrict__ x, const unsigned short* __restrict__ W1c,
    unsigned short* __restrict__ UV) {
  __shared__ __align__(16) unsigned short xt[128 * LDH2];
  const int tid = threadIdx.x;
  const int bid = blockIdx.x;
  const int ntile = bid >> 1, chalf = bid & 1;
  const int n0 = ntile * 128;
  const int lane = tid & 63, w = tid >> 6, m = lane & 15, q = lane >> 4;

  // stage x tile: f32 -> bf16, coalesced (16 threads per 128-f32 row)
  const int kb = (tid & 15) * 8;   // k-chunk in shorts
  const int e0 = tid >> 4;         // 0..15
#pragma unroll
  for (int i = 0; i < 8; ++i) {
    int r = e0 + 16 * i;
    int n = n0 + r; if (n >= N_NODES) n = N_NODES - 1;
    const float* p = x + n * 128 + kb;
    f32x4 g0 = *(const f32x4*)p, g1 = *(const f32x4*)(p + 4);
    short8 s;
#pragma unroll
    for (int j = 0; j < 4; ++j) { s[j] = (short)f2bf_u(g0[j]); s[4 + j] = (short)f2bf_u(g1[j]); }
    *(short8*)&xt[r * LDH2 + kb] = s;
  }

  int w1o[4];
#pragma unroll
  for (int nt = 0; nt < 4; ++nt) w1o[nt] = (chalf * 256 + (w * 4 + nt) * 16 + m) * 128 + q * 8;
  short8 wa[2][4];
#pragma unroll
  for (int nt = 0; nt < 4; ++nt) wa[0][nt] = *(const short8*)&W1c[w1o[nt]];

  __syncthreads();

  f32x4 acc[4][8];
#pragma unroll
  for (int nt = 0; nt < 4; ++nt)
#pragma unroll
    for (int mt = 0; mt < 8; ++mt) acc[nt][mt] = (f32x4){0.f, 0.f, 0.f, 0.f};

#pragma unroll
  for (int kk = 0; kk < 4; ++kk) {
    const int cur = kk & 1, nx = cur ^ 1;
    if (kk < 3) {
#pragma unroll
      for (int nt = 0; nt < 4; ++nt) wa[nx][nt] = *(const short8*)&W1c[w1o[nt] + (kk + 1) * 32];
    }
    short8 f[8];
#pragma unroll
    for (int mt = 0; mt < 8; ++mt)
      f[mt] = *(const short8*)&xt[(mt * 16 + m) * LDH2 + kk * 32 + q * 8];
#pragma unroll
    for (int nt = 0; nt < 4; ++nt)
#pragma unroll
      for (int mt = 0; mt < 8; ++mt)
        acc[nt][mt] = __builtin_amdgcn_mfma_f32_16x16x32_bf16(wa[cur][nt], f[mt], acc[nt][mt], 0, 0, 0);
  }

  // store f16 (no bias, no relu here)
#pragma unroll
  for (int nt = 0; nt < 4; ++nt)
#pragma unroll
    for (int mt = 0; mt < 8; ++mt) {
      int n = n0 + mt * 16 + m;
      if (n < N_NODES) {
        union { _Float16 h[4]; uint2 u; } pk;
#pragma unroll
        for (int r = 0; r < 4; ++r) pk.h[r] = (_Float16)acc[nt][mt][r];
        *(uint2*)&UV[n * 512 + chalf * 256 + w * 64 + nt * 16 + q * 4] = pk.u;
      }
    }
}

// ---- edge kernel: gather u[src],v[dst] (f16), relu(u+v+b1) -> LDS, W2-in-regs MFMA ----
// 96-edge tiles (exact), zero weight streaming, out stores non-temporal.
__global__ __launch_bounds__(256, 2) void edge_mlp(
    const unsigned short* __restrict__ UV, const int* __restrict__ ei,
    const unsigned short* __restrict__ W2t2, const unsigned short* __restrict__ b1h,
    const float* __restrict__ b2, float* __restrict__ out) {
  __shared__ __align__(16) unsigned short hid[ETILE * LDH3];  // 96 x 264 shorts
  const int tid = threadIdx.x;
  const int base = blockIdx.x * ETILE;
  const int lane = tid & 63, w = tid >> 6, m = lane & 15, q = lane >> 4;
  const int c = tid & 31;    // 16B chunk (k-dims c*8..c*8+8)
  const int e0 = tid >> 5;   // 0..7

  // tile-invariant: W2 frags + biases to registers (L2-hot, same addrs all blocks)
  half8 w2r[8];
  const int w2off = (w * 16 + m) * 256 + q * 8;
#pragma unroll
  for (int kk = 0; kk < 8; ++kk) w2r[kk] = *(const half8*)&W2t2[w2off + kk * 32];
  half8 bias = *(const half8*)&b1h[c * 8];
  f32x4 b2v = *(const f32x4*)&b2[w * 16 + q * 4];

  // edge indices: 12 rows per thread (rows e0 + 8i)
  int si[12], di[12];
#pragma unroll
  for (int i = 0; i < 12; ++i) {
    int e = base + e0 + 8 * i;
    si[i] = ei[e];
    di[i] = ei[E_TOTAL + e];
  }

  // gather + fused add/bias/relu in two 6-row groups (bounded reg pressure)
#pragma unroll
  for (int g = 0; g < 2; ++g) {
    half8 lu[6], lv[6];
#pragma unroll
    for (int i = 0; i < 6; ++i) {
      const int r = g * 6 + i;
      lu[i] = *(const half8*)&UV[(size_t)si[r] * 512 + c * 8];
      lv[i] = *(const half8*)&UV[(size_t)di[r] * 512 + 256 + c * 8];
    }
#pragma unroll
    for (int i = 0; i < 6; ++i) {
      const int r = g * 6 + i;
      half8 s = lu[i] + lv[i] + bias;   // v_pk_add_f16 x8
#pragma unroll
      for (int j = 0; j < 8; ++j) s[j] = s[j] > (_Float16)0 ? s[j] : (_Float16)0;
      *(half8*)&hid[(e0 + 8 * r) * LDH3 + c * 8] = s;
    }
  }

  __syncthreads();

  // phase 2: D[n2][e] = sum_k W2[n2][k] * hidden[e][k]  (f16 MFMA)
  f32x4 acc2[6];
#pragma unroll
  for (int mt = 0; mt < 6; ++mt) acc2[mt] = (f32x4){0.f, 0.f, 0.f, 0.f};
#pragma unroll
  for (int kk = 0; kk < 8; ++kk) {
#pragma unroll
    for (int mt = 0; mt < 6; ++mt) {
      half8 h = *(const half8*)&hid[(mt * 16 + m) * LDH3 + kk * 32 + q * 8];
      acc2[mt] = __builtin_amdgcn_mfma_f32_16x16x32_f16(w2r[kk], h, acc2[mt], 0, 0, 0);
    }
  }

#pragma unroll
  for (int mt = 0; mt < 6; ++mt) {
    f32x4 o;
#pragma unroll
    for (int r = 0; r < 4; ++r) o[r] = acc2[mt][r] + b2v[r];
    // non-temporal: keep the 150MB out-stream from evicting UV in L2/L3
    __builtin_nontemporal_store(o, (f32x4*)&out[(size_t)(base + mt * 16 + m) * 64 + w * 16 + q * 4]);
  }
}

extern "C" void kernel_launch(void* const* d_in, const int* in_sizes, int n_in,
                              void* d_out, int out_size, void* d_ws, size_t ws_size,
                              hipStream_t stream) {
  const float* x  = (const float*)d_in[0];
  const int*   ei = (const int*)d_in[1];
  const float* W1 = (const float*)d_in[2];
  const float* b1 = (const float*)d_in[3];
  const float* W2 = (const float*)d_in[4];
  const float* b2 = (const float*)d_in[5];
  float* out = (float*)d_out;

  unsigned short* W1c  = (unsigned short*)d_ws;      // [512][128] bf16
  unsigned short* W2t2 = W1c + 512 * 128;            // [64][256] f16
  unsigned short* b1h  = W2t2 + 64 * 256;            // [256] f16
  unsigned short* UV   = b1h + 256;                  // [50000][512] f16 (51.2 MB)

  prep<<<81, 256, 0, stream>>>(W1, W2, b1, W1c, W2t2, b1h);
  node_uv<<<NNT * 2, 256, 0, stream>>>(x, W1c, UV);
  edge_mlp<<<NETILES, 256, 0, stream>>>(UV, ei, W2t2, b1h, b2, out);
}

// Round 6
// 290.871 us; speedup vs baseline: 1.4418x; 1.0484x over previous
//
#include <hip/hip_runtime.h>

#define E_TOTAL 600000
#define N_NODES 50000
#define NETILES 9375        // 600000 / 64 exact, no tail
#define NNT 782             // ceil(50000/64) node tiles (last has 16 rows)
#define LDS_X 136           // node-kernel x-stage row stride (shorts), 272B
#define LDP 264             // pack/hidden row stride (shorts), 528B

typedef __attribute__((ext_vector_type(8))) short short8;
typedef __attribute__((ext_vector_type(8))) _Float16 half8;
typedef __attribute__((ext_vector_type(4))) float f32x4;

__device__ __forceinline__ unsigned f2bf_u(float f) {
  union { float f; unsigned u; } v; v.f = f;
  return (v.u + 0x7fffu + ((v.u >> 16) & 1u)) >> 16;  // RNE
}
__device__ __forceinline__ unsigned short f2h_u(float f) {
  union { _Float16 h; unsigned short u; } v; v.h = (_Float16)f;
  return v.u;
}

// ---- prep: W1 -> W1c[c][k] bf16 (c = n + 256*(k>=128), k'=k&127, [512][128]);
//            W2 -> W2t2[n][k] f16 [64][256]; b1 -> b1h f16 ----
__global__ __launch_bounds__(256) void prep(
    const float* __restrict__ W1, const float* __restrict__ W2,
    const float* __restrict__ b1,
    unsigned short* __restrict__ W1c, unsigned short* __restrict__ W2t2,
    unsigned short* __restrict__ b1h) {
  __shared__ float t[32][33];
  int bid = blockIdx.x;
  int tx = threadIdx.x & 31, ty = threadIdx.x >> 5;
  if (bid < 64) {
    int k0 = (bid >> 3) * 32, n0 = (bid & 7) * 32;
#pragma unroll
    for (int i = 0; i < 32; i += 8) t[ty + i][tx] = W1[(k0 + ty + i) * 256 + n0 + tx];
    __syncthreads();
    int coff = (k0 >= 128) ? 256 : 0;
#pragma unroll
    for (int i = 0; i < 32; i += 8)
      W1c[(n0 + ty + i + coff) * 128 + (k0 & 127) + tx] = (unsigned short)f2bf_u(t[tx][ty + i]);
  } else if (bid < 80) {
    int b = bid - 64;
    int k0 = (b >> 1) * 32, n0 = (b & 1) * 32;
#pragma unroll
    for (int i = 0; i < 32; i += 8) t[ty + i][tx] = W2[(k0 + ty + i) * 64 + n0 + tx];
    __syncthreads();
#pragma unroll
    for (int i = 0; i < 32; i += 8)
      W2t2[(n0 + ty + i) * 256 + k0 + tx] = f2h_u(t[tx][ty + i]);
  } else {
    b1h[threadIdx.x] = f2h_u(b1[threadIdx.x]);
  }
}

// ---- node kernel: UV[n][c] f16; c<256: u = x@W1[:128], c>=256: v = x@W1[128:] ----
// 64-node tile x one chalf per block (grid 1564, 3 blocks/CU). After the GEMM,
// acc is transpose-packed through LDS so UV stores are contiguous 512B rows
// (16B/lane coalesced) instead of 8B-at-1KB-stride dribble.
__global__ __launch_bounds__(256, 3) void node_uv(
    const float* __restrict__ x, const unsigned short* __restrict__ W1c,
    unsigned short* __restrict__ UV) {
  __shared__ __align__(16) unsigned short xt[64 * LDP];  // stage [64][136], then pack [64][264]
  const int tid = threadIdx.x;
  const int ntile = (int)blockIdx.x >> 1, chalf = blockIdx.x & 1;
  const int n0 = ntile * 64;
  const int lane = tid & 63, w = tid >> 6, m = lane & 15, q = lane >> 4;

  // stage x tile: f32 -> bf16, coalesced (16 threads per 128-f32 row)
  const int kb = (tid & 15) * 8;
  const int r0 = tid >> 4;  // 0..15
#pragma unroll
  for (int i = 0; i < 4; ++i) {
    int r = r0 + 16 * i;
    int n = n0 + r; if (n >= N_NODES) n = N_NODES - 1;
    const float* p = x + (size_t)n * 128 + kb;
    f32x4 g0 = *(const f32x4*)p, g1 = *(const f32x4*)(p + 4);
    short8 s;
#pragma unroll
    for (int j = 0; j < 4; ++j) { s[j] = (short)f2bf_u(g0[j]); s[4 + j] = (short)f2bf_u(g1[j]); }
    *(short8*)&xt[r * LDS_X + kb] = s;
  }

  int w1o[4];
#pragma unroll
  for (int nt = 0; nt < 4; ++nt) w1o[nt] = (chalf * 256 + (w * 4 + nt) * 16 + m) * 128 + q * 8;
  short8 wa[2][4];
#pragma unroll
  for (int nt = 0; nt < 4; ++nt) wa[0][nt] = *(const short8*)&W1c[w1o[nt]];

  __syncthreads();

  f32x4 acc[4][4];
#pragma unroll
  for (int nt = 0; nt < 4; ++nt)
#pragma unroll
    for (int mt = 0; mt < 4; ++mt) acc[nt][mt] = (f32x4){0.f, 0.f, 0.f, 0.f};

#pragma unroll
  for (int kk = 0; kk < 4; ++kk) {
    const int cur = kk & 1, nx = cur ^ 1;
    if (kk < 3) {
#pragma unroll
      for (int nt = 0; nt < 4; ++nt) wa[nx][nt] = *(const short8*)&W1c[w1o[nt] + (kk + 1) * 32];
    }
    short8 f[4];
#pragma unroll
    for (int mt = 0; mt < 4; ++mt)
      f[mt] = *(const short8*)&xt[(mt * 16 + m) * LDS_X + kk * 32 + q * 8];
#pragma unroll
    for (int nt = 0; nt < 4; ++nt)
#pragma unroll
      for (int mt = 0; mt < 4; ++mt)
        acc[nt][mt] = __builtin_amdgcn_mfma_f32_16x16x32_bf16(wa[cur][nt], f[mt], acc[nt][mt], 0, 0, 0);
  }

  __syncthreads();  // stage region dead

  // pack: row = local node (mt*16+m), col = (w*4+nt)*16 + q*4 + r  (f16 x4 -> uint2)
#pragma unroll
  for (int nt = 0; nt < 4; ++nt)
#pragma unroll
    for (int mt = 0; mt < 4; ++mt) {
      union { _Float16 h[4]; uint2 u; } pk;
#pragma unroll
      for (int r = 0; r < 4; ++r) pk.h[r] = (_Float16)acc[nt][mt][r];
      *(uint2*)&xt[(mt * 16 + m) * LDP + (w * 4 + nt) * 16 + q * 4] = pk.u;
    }

  __syncthreads();

  // coalesced copy to UV: thread covers row rr = tid>>2, chunks (tid&3)+4i (16B each)
  const int rr = tid >> 2, c8 = tid & 3;
  if (n0 + rr < N_NODES) {
    unsigned short* dst = UV + (size_t)(n0 + rr) * 512 + chalf * 256;
#pragma unroll
    for (int i = 0; i < 8; ++i) {
      int ch = c8 + 4 * i;
      *(short8*)&dst[ch * 8] = *(const short8*)&xt[rr * LDP + ch * 8];
    }
  }
}

// ---- edge kernel: gather u[src],v[dst] (f16), relu(u+v+b1) -> LDS, W2-in-regs MFMA ----
// 64-edge tiles, 4 blocks/CU (LDS 33.8KB, VGPR ~70): double the gather streams.
__global__ __launch_bounds__(256, 4) void edge_mlp(
    const unsigned short* __restrict__ UV, const int* __restrict__ ei,
    const unsigned short* __restrict__ W2t2, const unsigned short* __restrict__ b1h,
    const float* __restrict__ b2, float* __restrict__ out) {
  __shared__ __align__(16) unsigned short hid[64 * LDP];
  const int tid = threadIdx.x;
  const int base = blockIdx.x * 64;
  const int lane = tid & 63, w = tid >> 6, m = lane & 15, q = lane >> 4;
  const int c = tid & 31;    // 16B chunk (k-dims c*8..c*8+8)
  const int e0 = tid >> 5;   // 0..7

  // tile-invariant: W2 frags + biases (L2-hot, same addrs all blocks)
  half8 w2r[8];
  const int w2off = (w * 16 + m) * 256 + q * 8;
#pragma unroll
  for (int kk = 0; kk < 8; ++kk) w2r[kk] = *(const half8*)&W2t2[w2off + kk * 32];
  half8 bias = *(const half8*)&b1h[c * 8];
  f32x4 b2v = *(const f32x4*)&b2[w * 16 + q * 4];

  // edge indices: 8 rows per thread (rows e0 + 8i)
  int si[8], di[8];
#pragma unroll
  for (int i = 0; i < 8; ++i) {
    int e = base + e0 + 8 * i;
    si[i] = ei[e];
    di[i] = ei[E_TOTAL + e];
  }

  // gather + fused add/bias/relu in two 4-row groups (8 loads in flight each)
#pragma unroll
  for (int g = 0; g < 2; ++g) {
    half8 lu[4], lv[4];
#pragma unroll
    for (int i = 0; i < 4; ++i) {
      const int r = g * 4 + i;
      lu[i] = *(const half8*)&UV[(size_t)si[r] * 512 + c * 8];
      lv[i] = *(const half8*)&UV[(size_t)di[r] * 512 + 256 + c * 8];
    }
#pragma unroll
    for (int i = 0; i < 4; ++i) {
      const int r = g * 4 + i;
      half8 s = lu[i] + lv[i] + bias;   // v_pk_add_f16 x8
#pragma unroll
      for (int j = 0; j < 8; ++j) s[j] = s[j] > (_Float16)0 ? s[j] : (_Float16)0;
      *(half8*)&hid[(e0 + 8 * r) * LDP + c * 8] = s;
    }
  }

  __syncthreads();

  // phase 2: D[n2][e] = sum_k W2[n2][k] * hidden[e][k]  (f16 MFMA)
  f32x4 acc2[4];
#pragma unroll
  for (int mt = 0; mt < 4; ++mt) acc2[mt] = (f32x4){0.f, 0.f, 0.f, 0.f};
#pragma unroll
  for (int kk = 0; kk < 8; ++kk) {
#pragma unroll
    for (int mt = 0; mt < 4; ++mt) {
      half8 h = *(const half8*)&hid[(mt * 16 + m) * LDP + kk * 32 + q * 8];
      acc2[mt] = __builtin_amdgcn_mfma_f32_16x16x32_f16(w2r[kk], h, acc2[mt], 0, 0, 0);
    }
  }

#pragma unroll
  for (int mt = 0; mt < 4; ++mt) {
    f32x4 o;
#pragma unroll
    for (int r = 0; r < 4; ++r) o[r] = acc2[mt][r] + b2v[r];
    // non-temporal: keep the 150MB out-stream from evicting UV
    __builtin_nontemporal_store(o, (f32x4*)&out[(size_t)(base + mt * 16 + m) * 64 + w * 16 + q * 4]);
  }
}

extern "C" void kernel_launch(void* const* d_in, const int* in_sizes, int n_in,
                              void* d_out, int out_size, void* d_ws, size_t ws_size,
                              hipStream_t stream) {
  const float* x  = (const float*)d_in[0];
  const int*   ei = (const int*)d_in[1];
  const float* W1 = (const float*)d_in[2];
  const float* b1 = (const float*)d_in[3];
  const float* W2 = (const float*)d_in[4];
  const float* b2 = (const float*)d_in[5];
  float* out = (float*)d_out;

  unsigned short* W1c  = (unsigned short*)d_ws;      // [512][128] bf16
  unsigned short* W2t2 = W1c + 512 * 128;            // [64][256] f16
  unsigned short* b1h  = W2t2 + 64 * 256;            // [256] f16
  unsigned short* UV   = b1h + 256;                  // [50000][512] f16 (51.2 MB)

  prep<<<81, 256, 0, stream>>>(W1, W2, b1, W1c, W2t2, b1h);
  node_uv<<<NNT * 2, 256, 0, stream>>>(x, W1c, UV);
  edge_mlp<<<NETILES, 256, 0, stream>>>(UV, ei, W2t2, b1h, b2, out);
}